// Round 5
// baseline (373.364 us; speedup 1.0000x reference)
//
#include <hip/hip_runtime.h>
#include <hip/hip_fp16.h>

// R16: two-level line-dense placement. R15's flush (thread b copies bucket
// b's run) put 64 DIFFERENT buckets in each wave store-instr -> still 6.4M
// scattered line touches (~180us hidden below gather in top-5). Now:
//   pass1: partition into 49 super-buckets (4096 vnodes). Dense LDS stage +
//          per-element precomputed global position (stg2) -> consecutive
//          lanes write consecutive addresses (runs ~84 words). Coalesced.
//   pass2: split each super-bucket 16 ways into final 256-vnode buckets
//          (runs ~256 words, same stg/stg2 flush). Coalesced.
// gather (137us, at the ~46G random-line/s L3 fabric rate) unchanged.
//
// code1 = (vnode&4095)<<18 | vsrc ; code2 = code1 & 0x03FFFFFF
// vnode = 2*node+type (M=200000, 18 bits); final dst_local = bits 18-25.

#define SLICES  256
#define PSLICE  32
#define BSZ     256
#define NB_MAX  800
#define NSB_MAX 64
#define PCH     4096
#define LDSPAD  33
#define FXS     65536.0f
#define FXSI    (1.0f / 65536.0f)

// ---------------- 1. bucket histogram -> global btot ----------------
__global__ __launch_bounds__(256)
void bhist_kernel(const int* __restrict__ ei_n, const int* __restrict__ ei_s,
                  int* __restrict__ btot, int N, int En, int Es, int nb) {
    __shared__ int bh[NB_MAX];
    for (int b = threadIdx.x; b < nb; b += 256) bh[b] = 0;
    __syncthreads();
    const int type = blockIdx.y;
    const int E = type ? Es : En;
    const int* __restrict__ dst = (type ? ei_s + Es : ei_n + En);
    int per = ((E + SLICES - 1) / SLICES + 3) & ~3;
    const int e0 = blockIdx.x * per;
    const int e1 = min(e0 + per, E);
    int i = e0 + (int)threadIdx.x * 4;
    for (; i + 3 < e1; i += 256 * 4) {
        int4 d4 = *(const int4*)(dst + i);
        atomicAdd(&bh[d4.x >> 7], 1);   // bucket((2d+t)>>8) == d>>7, type-free
        atomicAdd(&bh[d4.y >> 7], 1);
        atomicAdd(&bh[d4.z >> 7], 1);
        atomicAdd(&bh[d4.w >> 7], 1);
    }
    for (; i < e1; ++i) atomicAdd(&bh[dst[i] >> 7], 1);
    __syncthreads();
    for (int b = threadIdx.x; b < nb; b += 256) {
        int v = bh[b];
        if (v) atomicAdd(&btot[b], v);
    }
}

// ------- 2. scan buckets: bucket_base/gcur (4-padded) + scur = SB starts -------
__global__ __launch_bounds__(1024)
void scan_kernel(const int* __restrict__ btot, int* __restrict__ bucket_base,
                 int* __restrict__ gcur, int* __restrict__ scur, int nb, int nsb) {
    __shared__ int s[1024];
    const int g = threadIdx.x;
    int c = (g < nb) ? ((btot[g] + 3) & ~3) : 0;
    s[g] = c;
    __syncthreads();
    for (int o = 1; o < 1024; o <<= 1) {
        int t = (g >= o) ? s[g - o] : 0;
        __syncthreads();
        s[g] += t;
        __syncthreads();
    }
    if (g < nb) {
        int b = s[g] - c;
        bucket_base[g] = b;
        gcur[g] = b;
        if ((g & 15) == 0) scur[g >> 4] = b;   // super-bucket start cursor
    }
}

// ---------------- 3. place pass 1: 49 super-buckets, coalesced flush -----------
__global__ __launch_bounds__(512)
void place1_kernel(const int* __restrict__ ei_n, const int* __restrict__ ei_s,
                   int* __restrict__ scur, unsigned int* __restrict__ codes1,
                   int En, int Es, int nsb) {
    __shared__ unsigned stg[PCH];        // 16 KB
    __shared__ unsigned stg2[PCH];       // 16 KB (global position per element)
    __shared__ int hist[NSB_MAX], sbse[NSB_MAX], gb[NSB_MAX];
    const int t = threadIdx.x;
    const int type = blockIdx.y;
    const int* __restrict__ ei = type ? ei_s : ei_n;
    const int E = type ? Es : En;
    int per = ((E + SLICES - 1) / SLICES + 7) & ~7;
    const int e0 = blockIdx.x * per;
    const int e1 = min(e0 + per, E);

    for (int c0 = e0; c0 < e1; c0 += PCH) {
        if (t < NSB_MAX) hist[t] = 0;
        __syncthreads();
        const int i = c0 + t * 8;
        int nv = e1 - i; nv = nv < 0 ? 0 : (nv > 8 ? 8 : nv);
        unsigned cd[8]; int bb[8], rk[8];
        if (nv == 8) {
            int4 sA = *(const int4*)(ei + i),     sB = *(const int4*)(ei + i + 4);
            int4 dA = *(const int4*)(ei + E + i), dB = *(const int4*)(ei + E + i + 4);
            int ss[8] = {sA.x, sA.y, sA.z, sA.w, sB.x, sB.y, sB.z, sB.w};
            int dd[8] = {dA.x, dA.y, dA.z, dA.w, dB.x, dB.y, dB.z, dB.w};
#pragma unroll
            for (int j = 0; j < 8; ++j) {
                int vd = 2 * dd[j] + type;
                bb[j] = vd >> 12;
                cd[j] = ((unsigned)(vd & 4095) << 18) | (unsigned)(2 * ss[j] + type);
            }
        } else {
            for (int j = 0; j < nv; ++j) {
                int vd = 2 * ei[E + i + j] + type;
                bb[j] = vd >> 12;
                cd[j] = ((unsigned)(vd & 4095) << 18) | (unsigned)(2 * ei[i + j] + type);
            }
        }
#pragma unroll
        for (int j = 0; j < 8; ++j)
            if (j < nv) rk[j] = atomicAdd(&hist[bb[j]], 1);
        __syncthreads();
        if (t < 64) {                        // wave-0 shfl scan over 49 bins
            int v = (t < nsb) ? hist[t] : 0;
            int x = v;
#pragma unroll
            for (int o = 1; o < 64; o <<= 1) {
                int n = __shfl_up(x, o, 64);
                if (t >= o) x += n;
            }
            if (t < nsb) {
                sbse[t] = x - v;
                gb[t] = v ? atomicAdd(&scur[t], v) : 0;
            }
        }
        __syncthreads();
#pragma unroll
        for (int j = 0; j < 8; ++j)
            if (j < nv) {
                int p = sbse[bb[j]] + rk[j];
                stg[p] = cd[j];
                stg2[p] = (unsigned)(gb[bb[j]] + rk[j]);
            }
        __syncthreads();
        const int tot = min(PCH, e1 - c0);
        for (int j = t; j < tot; j += 512)   // consecutive lanes -> run-ordered
            codes1[stg2[j]] = stg[j];
        __syncthreads();
    }
}

// ---------------- 4. place pass 2: split SB into 16 final buckets --------------
__global__ __launch_bounds__(512)
void place2_kernel(const unsigned int* __restrict__ codes1,
                   const int* __restrict__ bucket_base, const int* __restrict__ scur,
                   int* __restrict__ gcur, unsigned int* __restrict__ codes2, int nb) {
    __shared__ unsigned stg[PCH];
    __shared__ unsigned stg2[PCH];
    __shared__ int hist[16], bse[16], gb[16];
    const int t = threadIdx.x;
    const int sb = blockIdx.y;
    const int r0 = bucket_base[sb * 16];
    const int r1 = scur[sb];                 // end of pass-1 data for this SB
    const int len = r1 - r0;
    int per = ((len + PSLICE - 1) / PSLICE + 7) & ~7;
    const int e0 = r0 + blockIdx.x * per;
    const int e1 = min(e0 + per, r1);

    for (int c0 = e0; c0 < e1; c0 += PCH) {
        if (t < 16) hist[t] = 0;
        __syncthreads();
        const int i = c0 + t * 8;
        int nv = e1 - i; nv = nv < 0 ? 0 : (nv > 8 ? 8 : nv);
        unsigned cd[8]; int bb[8], rk[8];
        if (nv == 8) {
            uint4 a = *(const uint4*)(codes1 + i), b4 = *(const uint4*)(codes1 + i + 4);
            unsigned cc[8] = {a.x, a.y, a.z, a.w, b4.x, b4.y, b4.z, b4.w};
#pragma unroll
            for (int j = 0; j < 8; ++j) {
                bb[j] = (cc[j] >> 26) & 15;
                cd[j] = cc[j] & 0x03FFFFFFu;
            }
        } else {
            for (int j = 0; j < nv; ++j) {
                unsigned c = codes1[i + j];
                bb[j] = (c >> 26) & 15;
                cd[j] = c & 0x03FFFFFFu;
            }
        }
#pragma unroll
        for (int j = 0; j < 8; ++j)
            if (j < nv) rk[j] = atomicAdd(&hist[bb[j]], 1);
        __syncthreads();
        if (t < 16) {
            int v = hist[t], x = v;
#pragma unroll
            for (int o = 1; o < 16; o <<= 1) {
                int n = __shfl_up(x, o, 64);
                if (t >= o) x += n;
            }
            bse[t] = x - v;
            gb[t] = v ? atomicAdd(&gcur[sb * 16 + t], v) : 0;   // v==0 guards OOB
        }
        __syncthreads();
#pragma unroll
        for (int j = 0; j < 8; ++j)
            if (j < nv) {
                int p = bse[bb[j]] + rk[j];
                stg[p] = cd[j];
                stg2[p] = (unsigned)(gb[bb[j]] + rk[j]);
            }
        __syncthreads();
        const int tot = min(PCH, e1 - c0);
        for (int j = t; j < tot; j += 512)
            codes2[stg2[j]] = stg[j];
        __syncthreads();
    }
}

// ---------------- 5. per-vnode degree from binned codes ----------------
__global__ __launch_bounds__(256)
void dcount_kernel(const unsigned int* __restrict__ codes, const int* __restrict__ bucket_base,
                   const int* __restrict__ gcur, int* __restrict__ cnt, int M) {
    __shared__ int dcnt[BSZ];
    dcnt[threadIdx.x] = 0;
    __syncthreads();
    const int b = blockIdx.x;
    const int base = bucket_base[b];
    const int end = gcur[b];
    const int t0 = base + ((end - base) & ~3);
    for (int e = base + (int)threadIdx.x * 4; e < t0; e += 256 * 4) {
        uint4 c = *(const uint4*)(codes + e);
        atomicAdd(&dcnt[c.x >> 18], 1);
        atomicAdd(&dcnt[c.y >> 18], 1);
        atomicAdd(&dcnt[c.z >> 18], 1);
        atomicAdd(&dcnt[c.w >> 18], 1);
    }
    if ((int)threadIdx.x < end - t0) atomicAdd(&dcnt[codes[t0 + threadIdx.x] >> 18], 1);
    __syncthreads();
    const int vnode = b * BSZ + (int)threadIdx.x;
    if (vnode < M) cnt[vnode] = dcnt[threadIdx.x];
}

// ---------------- 6. xw: 1 node/thread, W^T LDS broadcast reads ----------------
__global__ __launch_bounds__(256)
void xw_kernel(const float* __restrict__ x,
               const float* __restrict__ Wn, const float* __restrict__ Ws,
               const int* __restrict__ cnt,
               __half2* __restrict__ xws, int N) {
    __shared__ float wtn[32 * 64];   // W^T: [h][k]
    __shared__ float wts[32 * 64];
    for (int i = threadIdx.x; i < 64 * 32; i += 256) {
        int k = i >> 5, h = i & 31;
        wtn[h * 64 + k] = Wn[i];
        wts[h * 64 + k] = Ws[i];
    }
    __syncthreads();
    int node = blockIdx.x * 256 + threadIdx.x;
    if (node >= N) return;

    float xr[64];
    const float4* x4 = (const float4*)(x + (size_t)node * 64);
#pragma unroll
    for (int q = 0; q < 16; ++q) {
        float4 v = x4[q];
        xr[4 * q] = v.x; xr[4 * q + 1] = v.y; xr[4 * q + 2] = v.z; xr[4 * q + 3] = v.w;
    }
    float dn = rsqrtf((float)cnt[2 * node] + 1.0f);
    float ds = rsqrtf((float)cnt[2 * node + 1] + 1.0f);

    unsigned pn[16], ps[16];
#pragma unroll
    for (int s2 = 0; s2 < 16; ++s2) {
        float a0n = 0.f, a1n = 0.f, a0s = 0.f, a1s = 0.f;
#pragma unroll
        for (int q = 0; q < 16; ++q) {
            float4 w0n = *(const float4*)&wtn[(2 * s2) * 64 + 4 * q];
            float4 w1n = *(const float4*)&wtn[(2 * s2 + 1) * 64 + 4 * q];
            float4 w0s = *(const float4*)&wts[(2 * s2) * 64 + 4 * q];
            float4 w1s = *(const float4*)&wts[(2 * s2 + 1) * 64 + 4 * q];
            float x0 = xr[4 * q], x1 = xr[4 * q + 1], x2 = xr[4 * q + 2], x3 = xr[4 * q + 3];
            a0n += x0 * w0n.x + x1 * w0n.y + x2 * w0n.z + x3 * w0n.w;
            a1n += x0 * w1n.x + x1 * w1n.y + x2 * w1n.z + x3 * w1n.w;
            a0s += x0 * w0s.x + x1 * w0s.y + x2 * w0s.z + x3 * w0s.w;
            a1s += x0 * w1s.x + x1 * w1s.y + x2 * w1s.z + x3 * w1s.w;
        }
        __half2 hn = __floats2half2_rn(a0n * dn, a1n * dn);
        __half2 hs = __floats2half2_rn(a0s * ds, a1s * ds);
        pn[s2] = *(unsigned*)&hn;
        ps[s2] = *(unsigned*)&hs;
    }
    uint4* on = (uint4*)(xws + (size_t)(2 * node) * 16);
    uint4* os = (uint4*)(xws + (size_t)(2 * node + 1) * 16);
#pragma unroll
    for (int q = 0; q < 4; ++q) {
        on[q] = make_uint4(pn[4 * q], pn[4 * q + 1], pn[4 * q + 2], pn[4 * q + 3]);
        os[q] = make_uint4(ps[4 * q], ps[4 * q + 1], ps[4 * q + 2], ps[4 * q + 3]);
    }
}

// ---------------- 7. gather: fixed-point LDS accumulate + fused epilogue -------
__global__ __launch_bounds__(512)
void gather_kernel(const unsigned int* __restrict__ codes, const int* __restrict__ bucket_base,
                   const int* __restrict__ gcur, const __half2* __restrict__ xws,
                   const int* __restrict__ cnt,
                   const float* __restrict__ b_n, const float* __restrict__ b_s,
                   const float* __restrict__ W_lin, const float* __restrict__ b_lin,
                   float* __restrict__ out, int N) {
    __shared__ int facc[BSZ * LDSPAD];   // 33.8 KB
    for (int i = threadIdx.x; i < BSZ * LDSPAD; i += 512) facc[i] = 0;
    __syncthreads();
    const int b = blockIdx.x;
    const int base = bucket_base[b];            // multiple of 4
    const int end = gcur[b];
    const int sl = threadIdx.x & 15;
    const int grp = threadIdx.x >> 4;           // 32 groups of 16 lanes

#define GA(cc) xws[(size_t)((cc) & 0x3FFFFu) * 16 + sl]
#define ACC_EDGE(cc, ww) do {                                                \
        float2 f_ = __half22float2(ww);                                      \
        int r_ = (int)((cc) >> 18) * LDSPAD + sl;                            \
        atomicAdd(&facc[r_],      __float2int_rn(f_.x * FXS));               \
        atomicAdd(&facc[r_ + 16], __float2int_rn(f_.y * FXS));               \
    } while (0)

    const int t0 = base + ((end - base) & ~15);
    for (int e = base + grp * 16; e < t0; e += 32 * 16) {
        uint4 c0 = *(const uint4*)(codes + e);
        uint4 c1 = *(const uint4*)(codes + e + 4);
        uint4 c2 = *(const uint4*)(codes + e + 8);
        uint4 c3 = *(const uint4*)(codes + e + 12);
        __half2 w0 = GA(c0.x), w1 = GA(c0.y), w2 = GA(c0.z), w3 = GA(c0.w);
        __half2 w4 = GA(c1.x), w5 = GA(c1.y), w6 = GA(c1.z), w7 = GA(c1.w);
        __half2 w8 = GA(c2.x), w9 = GA(c2.y), wA = GA(c2.z), wB = GA(c2.w);
        __half2 wC = GA(c3.x), wD = GA(c3.y), wE = GA(c3.z), wF = GA(c3.w);
        ACC_EDGE(c0.x, w0); ACC_EDGE(c0.y, w1); ACC_EDGE(c0.z, w2); ACC_EDGE(c0.w, w3);
        ACC_EDGE(c1.x, w4); ACC_EDGE(c1.y, w5); ACC_EDGE(c1.z, w6); ACC_EDGE(c1.w, w7);
        ACC_EDGE(c2.x, w8); ACC_EDGE(c2.y, w9); ACC_EDGE(c2.z, wA); ACC_EDGE(c2.w, wB);
        ACC_EDGE(c3.x, wC); ACC_EDGE(c3.y, wD); ACC_EDGE(c3.z, wE); ACC_EDGE(c3.w, wF);
    }
    for (int e = t0 + grp; e < end; e += 32) {
        unsigned c = codes[e];
        __half2 w = GA(c);
        ACC_EDGE(c, w);
    }
#undef ACC_EDGE
#undef GA

    __syncthreads();
    const float bn0 = b_n[2 * sl], bn1 = b_n[2 * sl + 1];
    const float bs0 = b_s[2 * sl], bs1 = b_s[2 * sl + 1];
    const float wl0 = W_lin[2 * sl], wl1 = W_lin[2 * sl + 1];
    const float bl  = b_lin[0];
    for (int p = grp; p < 128; p += 32) {
        int node = b * 128 + p;
        if (node >= N) break;
        int rn = (2 * p) * LDSPAD, rs = rn + LDSPAD;
        float anx = (float)facc[rn + sl] * FXSI, any_ = (float)facc[rn + 16 + sl] * FXSI;
        float asx = (float)facc[rs + sl] * FXSI, asy  = (float)facc[rs + 16 + sl] * FXSI;
        float2 ns = __half22float2(xws[(size_t)(2 * node) * 16 + sl]);
        float2 ss = __half22float2(xws[(size_t)(2 * node + 1) * 16 + sl]);
        float dn  = rsqrtf((float)cnt[2 * node] + 1.0f);
        float dsv = rsqrtf((float)cnt[2 * node + 1] + 1.0f);
        float h0 = (anx + ns.x) * dn + bn0 + (asx + ss.x) * dsv + bs0;
        float h1 = (any_ + ns.y) * dn + bn1 + (asy + ss.y) * dsv + bs1;
        float pr = fmaxf(h0, 0.f) * wl0 + fmaxf(h1, 0.f) * wl1;
#pragma unroll
        for (int off = 8; off > 0; off >>= 1) pr += __shfl_xor(pr, off, 16);
        if (sl == 0) out[node] = pr + bl;
    }
}

extern "C" void kernel_launch(void* const* d_in, const int* in_sizes, int n_in,
                              void* d_out, int out_size, void* d_ws, size_t ws_size,
                              hipStream_t stream) {
    const float* x     = (const float*)d_in[0];
    const int*   ei_n  = (const int*)d_in[1];
    const int*   ei_s  = (const int*)d_in[2];
    const float* W_n   = (const float*)d_in[3];
    const float* b_n   = (const float*)d_in[4];
    const float* W_s   = (const float*)d_in[5];
    const float* b_s   = (const float*)d_in[6];
    const float* W_lin = (const float*)d_in[7];
    const float* b_lin = (const float*)d_in[8];
    float* out = (float*)d_out;

    const int N  = in_sizes[0] / 64;   // 100000
    const int En = in_sizes[1] / 2;    // 3200000
    const int Es = in_sizes[2] / 2;    // 3200000
    const int M  = 2 * N;              // 200000 vnodes (vn = 2*node + type)
    const int nb  = (M + BSZ - 1) / BSZ;           // 782 buckets
    const int nsb = (M + 4095) / 4096;             // 49 super-buckets
    const size_t Etot = (size_t)En + (size_t)Es;   // 6.4M

    // Workspace (~66 MB): btot[nb] | bucket_base[nb] | gcur[nb] | scur[64]
    // | cnt[M] | codes1[Etot+4nb] | codes2[Etot+4nb] | xws[16*M half2]
    int* btot        = (int*)d_ws;
    int* bucket_base = btot + nb;
    int* gcur        = bucket_base + nb;
    int* scur        = gcur + nb;
    int* cnt         = scur + 64;
    uintptr_t pc1 = (uintptr_t)(cnt + M);
    pc1 = (pc1 + 15) & ~(uintptr_t)15;
    unsigned int* codes1 = (unsigned int*)pc1;
    unsigned int* codes2 = codes1 + Etot + 4 * (size_t)nb;
    __half2* xws = (__half2*)(codes2 + Etot + 4 * (size_t)nb);

    hipMemsetAsync(btot, 0, (size_t)nb * sizeof(int), stream);

    bhist_kernel<<<dim3(SLICES, 2), 256, 0, stream>>>(ei_n, ei_s, btot, N, En, Es, nb);
    scan_kernel<<<1, 1024, 0, stream>>>(btot, bucket_base, gcur, scur, nb, nsb);
    place1_kernel<<<dim3(SLICES, 2), 512, 0, stream>>>(ei_n, ei_s, scur, codes1,
                                                       En, Es, nsb);
    place2_kernel<<<dim3(PSLICE, nsb), 512, 0, stream>>>(codes1, bucket_base, scur,
                                                         gcur, codes2, nb);
    dcount_kernel<<<nb, 256, 0, stream>>>(codes2, bucket_base, gcur, cnt, M);
    xw_kernel<<<(N + 255) / 256, 256, 0, stream>>>(x, W_n, W_s, cnt, xws, N);
    gather_kernel<<<nb, 512, 0, stream>>>(codes2, bucket_base, gcur, xws, cnt,
                                          b_n, b_s, W_lin, b_lin, out, N);
}

// Round 7
// 301.933 us; speedup vs baseline: 1.2366x; 1.2366x over previous
//
#include <hip/hip_runtime.h>
#include <hip/hip_fp16.h>

// R18 = R17 resubmitted verbatim (R17 bench died with "MI355X container
// failed twice" = infra failure, no verification/profile data; kernel
// re-audited for hangs/OOB/alignment/barrier-divergence -> clean).
//
// R17: collapse 8 dispatches -> 4. Evidence: non-gather budget stayed
// ~230-240us across R13-R16 regardless of place implementation (even +50MB
// extra traffic in R16 cost +2us) => fixed per-dispatch launch/drain cost
// (~10-15us each) + ~100us real helper work, not any single hot kernel.
//  - Fixed-capacity buckets: bucket b owns codes[b*CAP2 ..), CAP2=9216
//    (mean 8184, sigma~90 -> 11-sigma slack). bucket_base static =>
//    bhist + scan + btot deleted.
//  - Single-pass place (LDS radix, position-ordered flush). place2 deleted.
//  - dcount fused into xw (dcxw): bucket b = nodes [128b,128b+128); degree
//    LDS-local, W-projection reads it directly. Separate dcount deleted.
// Pipeline: memset(3KB goff) -> place -> dcxw -> gather.
//
// code = (dst_local<<18) | vsrc; dst_local = 2*(d&127)+type; vsrc = 2*s+type
// vnode = 2*node+type; bucket = vnode>>8 = d>>7 (type-free).

#define SLICES 256
#define BSZ    256            // vnodes per bucket (=128 node pairs)
#define NB_MAX 800
#define CAP2   9216           // words reserved per bucket (mult of 4)
#define PCH    4096           // place: edges per chunk (512 thr x 8)
#define LDSPAD 33
#define FXS    65536.0f
#define FXSI   (1.0f / 65536.0f)

// ---------------- 1. place: LDS radix partition into fixed-cap buckets --------
__global__ __launch_bounds__(512)
void place_kernel(const int* __restrict__ ei_n, const int* __restrict__ ei_s,
                  int* __restrict__ goff, unsigned int* __restrict__ codes,
                  int En, int Es, int nb) {
    __shared__ unsigned stg[PCH];        // 16 KB
    __shared__ unsigned stg2[PCH];       // 16 KB (global position per element)
    __shared__ int hist[NB_MAX];
    __shared__ int base[NB_MAX];
    __shared__ int gb[NB_MAX];
    __shared__ int h2[NB_MAX / 2];
    const int t = threadIdx.x;
    const int type = blockIdx.y;
    const int* __restrict__ ei = type ? ei_s : ei_n;
    const int E = type ? Es : En;
    int per = ((E + SLICES - 1) / SLICES + 7) & ~7;
    const int e0 = blockIdx.x * per;
    const int e1 = min(e0 + per, E);
    const int P = (nb + 1) >> 1;

    for (int c0 = e0; c0 < e1; c0 += PCH) {
        for (int b = t; b < nb; b += 512) hist[b] = 0;
        __syncthreads();

        const int i = c0 + t * 8;
        int nv = e1 - i; nv = nv < 0 ? 0 : (nv > 8 ? 8 : nv);
        unsigned cd[8]; int bb[8], rk[8];
        if (nv == 8) {
            int4 sA = *(const int4*)(ei + i),     sB = *(const int4*)(ei + i + 4);
            int4 dA = *(const int4*)(ei + E + i), dB = *(const int4*)(ei + E + i + 4);
            int ss[8] = {sA.x, sA.y, sA.z, sA.w, sB.x, sB.y, sB.z, sB.w};
            int dd[8] = {dA.x, dA.y, dA.z, dA.w, dB.x, dB.y, dB.z, dB.w};
#pragma unroll
            for (int j = 0; j < 8; ++j) {
                bb[j] = dd[j] >> 7;
                cd[j] = ((unsigned)(2 * (dd[j] & 127) + type) << 18)
                      | (unsigned)(2 * ss[j] + type);
            }
        } else {
            for (int j = 0; j < nv; ++j) {
                int sv = ei[i + j], dv = ei[E + i + j];
                bb[j] = dv >> 7;
                cd[j] = ((unsigned)(2 * (dv & 127) + type) << 18)
                      | (unsigned)(2 * sv + type);
            }
        }
#pragma unroll
        for (int j = 0; j < 8; ++j)
            if (j < nv) rk[j] = atomicAdd(&hist[bb[j]], 1);
        __syncthreads();

        // exclusive scan of hist[0..nb): 2-elem pairing + Hillis on h2[0..P)
        if (t < P) {
            int a = hist[2 * t];
            int b2 = (2 * t + 1 < nb) ? hist[2 * t + 1] : 0;
            h2[t] = a + b2;
        }
        __syncthreads();
        for (int o = 1; o < P; o <<= 1) {
            int v = (t < P && t >= o) ? h2[t - o] : 0;
            __syncthreads();
            if (t < P) h2[t] += v;
            __syncthreads();
        }
        if (t < P) {
            int a = hist[2 * t];
            int b2 = (2 * t + 1 < nb) ? hist[2 * t + 1] : 0;
            int inc = h2[t];
            base[2 * t] = inc - a - b2;
            if (2 * t + 1 < nb) base[2 * t + 1] = inc - b2;
        }
        __syncthreads();

        // reserve global space in the fixed-cap region (1 atomic/bucket/chunk)
        for (int b = t; b < nb; b += 512) {
            int c = hist[b];
            gb[b] = c ? (b * CAP2 + atomicAdd(&goff[b], c)) : 0;
        }
        __syncthreads();
        // dense LDS scatter + precomputed global position
#pragma unroll
        for (int j = 0; j < 8; ++j)
            if (j < nv) {
                int p = base[bb[j]] + rk[j];
                stg[p] = cd[j];
                stg2[p] = (unsigned)(gb[bb[j]] + rk[j]);
            }
        __syncthreads();
        const int tot = min(PCH, e1 - c0);
        for (int j = t; j < tot; j += 512)   // consecutive lanes, run-ordered
            codes[stg2[j]] = stg[j];
        __syncthreads();
    }
}

// ---------------- 2. dcxw: per-bucket degree count + fused W-projection --------
// bucket b covers vnodes [256b,256b+256) = nodes [128b,128b+128).
// Phase 1: dcnt from codes. Phase 2: write cnt. Phase 3: xw for own nodes
// using LDS dcnt (2 threads/node, 8 output half2-pairs each).
__global__ __launch_bounds__(256)
void dcxw_kernel(const unsigned int* __restrict__ codes, const int* __restrict__ goff,
                 const float* __restrict__ x,
                 const float* __restrict__ Wn, const float* __restrict__ Ws,
                 int* __restrict__ cnt, __half2* __restrict__ xws, int N, int M) {
    __shared__ float wtn[32 * 64];   // W^T: [h][k]
    __shared__ float wts[32 * 64];
    __shared__ int dcnt[BSZ];
    const int t = threadIdx.x;
    dcnt[t] = 0;
    for (int i = t; i < 64 * 32; i += 256) {
        int k = i >> 5, h = i & 31;
        wtn[h * 64 + k] = Wn[i];
        wts[h * 64 + k] = Ws[i];
    }
    __syncthreads();

    const int b = blockIdx.x;
    const int base = b * CAP2;
    const int end = base + goff[b];
    const int t0 = base + ((end - base) & ~3);
    for (int e = base + t * 4; e < t0; e += 256 * 4) {
        uint4 c = *(const uint4*)(codes + e);
        atomicAdd(&dcnt[c.x >> 18], 1);
        atomicAdd(&dcnt[c.y >> 18], 1);
        atomicAdd(&dcnt[c.z >> 18], 1);
        atomicAdd(&dcnt[c.w >> 18], 1);
    }
    if (t < end - t0) atomicAdd(&dcnt[codes[t0 + t] >> 18], 1);
    __syncthreads();

    const int vnode = b * BSZ + t;
    if (vnode < M) cnt[vnode] = dcnt[t];

    // xw: thread t -> node p = t>>1, output half = t&1 (s2 in [8h, 8h+8))
    const int p = t >> 1, half = t & 1;
    const int node = b * 128 + p;
    if (node >= N) return;

    float xr[64];
    const float4* x4 = (const float4*)(x + (size_t)node * 64);
#pragma unroll
    for (int q = 0; q < 16; ++q) {
        float4 v = x4[q];
        xr[4 * q] = v.x; xr[4 * q + 1] = v.y; xr[4 * q + 2] = v.z; xr[4 * q + 3] = v.w;
    }
    float dn = rsqrtf((float)dcnt[2 * p] + 1.0f);
    float ds = rsqrtf((float)dcnt[2 * p + 1] + 1.0f);

    unsigned pn[8], ps[8];
#pragma unroll
    for (int s2i = 0; s2i < 8; ++s2i) {
        const int s2 = half * 8 + s2i;
        float a0n = 0.f, a1n = 0.f, a0s = 0.f, a1s = 0.f;
#pragma unroll
        for (int q = 0; q < 16; ++q) {
            float4 w0n = *(const float4*)&wtn[(2 * s2) * 64 + 4 * q];
            float4 w1n = *(const float4*)&wtn[(2 * s2 + 1) * 64 + 4 * q];
            float4 w0s = *(const float4*)&wts[(2 * s2) * 64 + 4 * q];
            float4 w1s = *(const float4*)&wts[(2 * s2 + 1) * 64 + 4 * q];
            float x0 = xr[4 * q], x1 = xr[4 * q + 1], x2 = xr[4 * q + 2], x3 = xr[4 * q + 3];
            a0n += x0 * w0n.x + x1 * w0n.y + x2 * w0n.z + x3 * w0n.w;
            a1n += x0 * w1n.x + x1 * w1n.y + x2 * w1n.z + x3 * w1n.w;
            a0s += x0 * w0s.x + x1 * w0s.y + x2 * w0s.z + x3 * w0s.w;
            a1s += x0 * w1s.x + x1 * w1s.y + x2 * w1s.z + x3 * w1s.w;
        }
        __half2 hn = __floats2half2_rn(a0n * dn, a1n * dn);
        __half2 hs = __floats2half2_rn(a0s * ds, a1s * ds);
        pn[s2i] = *(unsigned*)&hn;
        ps[s2i] = *(unsigned*)&hs;
    }
    uint4* on = (uint4*)(xws + (size_t)(2 * node) * 16 + half * 8);
    uint4* os = (uint4*)(xws + (size_t)(2 * node + 1) * 16 + half * 8);
    on[0] = make_uint4(pn[0], pn[1], pn[2], pn[3]);
    on[1] = make_uint4(pn[4], pn[5], pn[6], pn[7]);
    os[0] = make_uint4(ps[0], ps[1], ps[2], ps[3]);
    os[1] = make_uint4(ps[4], ps[5], ps[6], ps[7]);
}

// ---------------- 3. gather: fixed-point LDS accumulate + fused epilogue -------
__global__ __launch_bounds__(512)
void gather_kernel(const unsigned int* __restrict__ codes, const int* __restrict__ goff,
                   const __half2* __restrict__ xws, const int* __restrict__ cnt,
                   const float* __restrict__ b_n, const float* __restrict__ b_s,
                   const float* __restrict__ W_lin, const float* __restrict__ b_lin,
                   float* __restrict__ out, int N) {
    __shared__ int facc[BSZ * LDSPAD];   // 33.8 KB
    for (int i = threadIdx.x; i < BSZ * LDSPAD; i += 512) facc[i] = 0;
    __syncthreads();
    const int b = blockIdx.x;
    const int base = b * CAP2;                  // multiple of 4
    const int end = base + goff[b];
    const int sl = threadIdx.x & 15;
    const int grp = threadIdx.x >> 4;           // 32 groups of 16 lanes

#define GA(cc) xws[(size_t)((cc) & 0x3FFFFu) * 16 + sl]
#define ACC_EDGE(cc, ww) do {                                                \
        float2 f_ = __half22float2(ww);                                      \
        int r_ = (int)((cc) >> 18) * LDSPAD + sl;                            \
        atomicAdd(&facc[r_],      __float2int_rn(f_.x * FXS));               \
        atomicAdd(&facc[r_ + 16], __float2int_rn(f_.y * FXS));               \
    } while (0)

    const int t0 = base + ((end - base) & ~15);
    for (int e = base + grp * 16; e < t0; e += 32 * 16) {
        uint4 c0 = *(const uint4*)(codes + e);
        uint4 c1 = *(const uint4*)(codes + e + 4);
        uint4 c2 = *(const uint4*)(codes + e + 8);
        uint4 c3 = *(const uint4*)(codes + e + 12);
        __half2 w0 = GA(c0.x), w1 = GA(c0.y), w2 = GA(c0.z), w3 = GA(c0.w);
        __half2 w4 = GA(c1.x), w5 = GA(c1.y), w6 = GA(c1.z), w7 = GA(c1.w);
        __half2 w8 = GA(c2.x), w9 = GA(c2.y), wA = GA(c2.z), wB = GA(c2.w);
        __half2 wC = GA(c3.x), wD = GA(c3.y), wE = GA(c3.z), wF = GA(c3.w);
        ACC_EDGE(c0.x, w0); ACC_EDGE(c0.y, w1); ACC_EDGE(c0.z, w2); ACC_EDGE(c0.w, w3);
        ACC_EDGE(c1.x, w4); ACC_EDGE(c1.y, w5); ACC_EDGE(c1.z, w6); ACC_EDGE(c1.w, w7);
        ACC_EDGE(c2.x, w8); ACC_EDGE(c2.y, w9); ACC_EDGE(c2.z, wA); ACC_EDGE(c2.w, wB);
        ACC_EDGE(c3.x, wC); ACC_EDGE(c3.y, wD); ACC_EDGE(c3.z, wE); ACC_EDGE(c3.w, wF);
    }
    for (int e = t0 + grp; e < end; e += 32) {
        unsigned c = codes[e];
        __half2 w = GA(c);
        ACC_EDGE(c, w);
    }
#undef ACC_EDGE
#undef GA

    __syncthreads();
    const float bn0 = b_n[2 * sl], bn1 = b_n[2 * sl + 1];
    const float bs0 = b_s[2 * sl], bs1 = b_s[2 * sl + 1];
    const float wl0 = W_lin[2 * sl], wl1 = W_lin[2 * sl + 1];
    const float bl  = b_lin[0];
    for (int p = grp; p < 128; p += 32) {
        int node = b * 128 + p;
        if (node >= N) break;
        int rn = (2 * p) * LDSPAD, rs = rn + LDSPAD;
        float anx = (float)facc[rn + sl] * FXSI, any_ = (float)facc[rn + 16 + sl] * FXSI;
        float asx = (float)facc[rs + sl] * FXSI, asy  = (float)facc[rs + 16 + sl] * FXSI;
        float2 ns = __half22float2(xws[(size_t)(2 * node) * 16 + sl]);
        float2 ss = __half22float2(xws[(size_t)(2 * node + 1) * 16 + sl]);
        float dn  = rsqrtf((float)cnt[2 * node] + 1.0f);
        float dsv = rsqrtf((float)cnt[2 * node + 1] + 1.0f);
        float h0 = (anx + ns.x) * dn + bn0 + (asx + ss.x) * dsv + bs0;
        float h1 = (any_ + ns.y) * dn + bn1 + (asy + ss.y) * dsv + bs1;
        float pr = fmaxf(h0, 0.f) * wl0 + fmaxf(h1, 0.f) * wl1;
#pragma unroll
        for (int off = 8; off > 0; off >>= 1) pr += __shfl_xor(pr, off, 16);
        if (sl == 0) out[node] = pr + bl;
    }
}

extern "C" void kernel_launch(void* const* d_in, const int* in_sizes, int n_in,
                              void* d_out, int out_size, void* d_ws, size_t ws_size,
                              hipStream_t stream) {
    const float* x     = (const float*)d_in[0];
    const int*   ei_n  = (const int*)d_in[1];
    const int*   ei_s  = (const int*)d_in[2];
    const float* W_n   = (const float*)d_in[3];
    const float* b_n   = (const float*)d_in[4];
    const float* W_s   = (const float*)d_in[5];
    const float* b_s   = (const float*)d_in[6];
    const float* W_lin = (const float*)d_in[7];
    const float* b_lin = (const float*)d_in[8];
    float* out = (float*)d_out;

    const int N  = in_sizes[0] / 64;   // 100000
    const int En = in_sizes[1] / 2;    // 3200000
    const int Es = in_sizes[2] / 2;    // 3200000
    const int M  = 2 * N;              // 200000 vnodes (vn = 2*node + type)
    const int nb = (M + BSZ - 1) / BSZ;            // 782 buckets

    // Workspace (~43 MB): goff[1024] | cnt[M] | codes[nb*CAP2] (16B aligned)
    // | xws[16*M half2]
    int* goff = (int*)d_ws;
    int* cnt  = goff + 1024;
    uintptr_t pc = (uintptr_t)(cnt + M);
    pc = (pc + 15) & ~(uintptr_t)15;
    unsigned int* codes = (unsigned int*)pc;
    __half2* xws = (__half2*)(codes + (size_t)nb * CAP2);

    hipMemsetAsync(goff, 0, (size_t)nb * sizeof(int), stream);

    place_kernel<<<dim3(SLICES, 2), 512, 0, stream>>>(ei_n, ei_s, goff, codes,
                                                      En, Es, nb);
    dcxw_kernel<<<nb, 256, 0, stream>>>(codes, goff, x, W_n, W_s, cnt, xws, N, M);
    gather_kernel<<<nb, 512, 0, stream>>>(codes, goff, xws, cnt,
                                          b_n, b_s, W_lin, b_lin, out, N);
}

// Round 8
// 293.936 us; speedup vs baseline: 1.2702x; 1.0272x over previous
//
#include <hip/hip_runtime.h>
#include <hip/hip_fp16.h>

// R19: place v2 — kill global-reservation atomic contention.
// R17's place reserved per CHUNK: 1562 chunks x 782 buckets ~= 1.22M atomicAdd
// concentrated on 49 lines (782-int goff) ~= 25K serialized RMWs/line ~= most
// of place's ~95us. Now: pass A = slice-total LDS hist (one streaming read of
// dst), ONE reservation per block (400K atomics, 3x fewer), pass B = per-chunk
// ranks + LDS cursor snapshots -> stg2 global positions -> dense coalesced
// flush (unchanged). dcxw + gather unchanged from R17.
//
// code = (dst_local<<18) | vsrc; dst_local = 2*(d&127)+type; vsrc = 2*s+type
// vnode = 2*node+type; bucket = vnode>>8 = d>>7 (type-free).

#define SLICES 256
#define BSZ    256            // vnodes per bucket (=128 node pairs)
#define NB_MAX 800
#define CAP2   9216           // words reserved per bucket (mult of 4)
#define PCH    4096           // place: edges per chunk (512 thr x 8)
#define LDSPAD 33
#define FXS    65536.0f
#define FXSI   (1.0f / 65536.0f)

// ---------------- 1. place: 2-pass LDS radix, 1 reservation/block -------------
__global__ __launch_bounds__(512)
void place_kernel(const int* __restrict__ ei_n, const int* __restrict__ ei_s,
                  int* __restrict__ goff, unsigned int* __restrict__ codes,
                  int En, int Es, int nb) {
    __shared__ unsigned stg[PCH];        // 16 KB
    __shared__ unsigned stg2[PCH];       // 16 KB global position per element
    __shared__ int histT[NB_MAX];        // slice-total hist
    __shared__ int cur[NB_MAX];          // running global cursors
    __shared__ int histC[NB_MAX];        // per-chunk hist
    __shared__ int baseC[NB_MAX];        // per-chunk stage base
    __shared__ int gbC[NB_MAX];          // per-chunk cursor snapshot
    __shared__ int h2[NB_MAX / 2];
    const int t = threadIdx.x;
    const int type = blockIdx.y;
    const int* __restrict__ ei = type ? ei_s : ei_n;
    const int E = type ? Es : En;
    int per = ((E + SLICES - 1) / SLICES + 7) & ~7;
    const int e0 = blockIdx.x * per;
    const int e1 = min(e0 + per, E);
    const int P = (nb + 1) >> 1;

    for (int b = t; b < nb; b += 512) histT[b] = 0;
    __syncthreads();

    // ---- pass A: slice-total histogram (dst stream only, no inner barriers)
    for (int c0 = e0; c0 < e1; c0 += PCH) {
        const int i = c0 + t * 8;
        int nv = e1 - i; nv = nv < 0 ? 0 : (nv > 8 ? 8 : nv);
        if (nv == 8) {
            int4 dA = *(const int4*)(ei + E + i), dB = *(const int4*)(ei + E + i + 4);
            atomicAdd(&histT[dA.x >> 7], 1);
            atomicAdd(&histT[dA.y >> 7], 1);
            atomicAdd(&histT[dA.z >> 7], 1);
            atomicAdd(&histT[dA.w >> 7], 1);
            atomicAdd(&histT[dB.x >> 7], 1);
            atomicAdd(&histT[dB.y >> 7], 1);
            atomicAdd(&histT[dB.z >> 7], 1);
            atomicAdd(&histT[dB.w >> 7], 1);
        } else {
            for (int j = 0; j < nv; ++j) atomicAdd(&histT[ei[E + i + j] >> 7], 1);
        }
    }
    __syncthreads();

    // ---- single global reservation per block
    for (int b = t; b < nb; b += 512) {
        int c = histT[b];
        cur[b] = b * CAP2 + (c ? atomicAdd(&goff[b], c) : 0);
    }
    __syncthreads();

    // ---- pass B: per-chunk rank + stage + coalesced flush
    for (int c0 = e0; c0 < e1; c0 += PCH) {
        for (int b = t; b < nb; b += 512) histC[b] = 0;
        __syncthreads();

        const int i = c0 + t * 8;
        int nv = e1 - i; nv = nv < 0 ? 0 : (nv > 8 ? 8 : nv);
        unsigned cd[8]; int bb[8], rk[8];
        if (nv == 8) {
            int4 sA = *(const int4*)(ei + i),     sB = *(const int4*)(ei + i + 4);
            int4 dA = *(const int4*)(ei + E + i), dB = *(const int4*)(ei + E + i + 4);
            int ss[8] = {sA.x, sA.y, sA.z, sA.w, sB.x, sB.y, sB.z, sB.w};
            int dd[8] = {dA.x, dA.y, dA.z, dA.w, dB.x, dB.y, dB.z, dB.w};
#pragma unroll
            for (int j = 0; j < 8; ++j) {
                bb[j] = dd[j] >> 7;
                cd[j] = ((unsigned)(2 * (dd[j] & 127) + type) << 18)
                      | (unsigned)(2 * ss[j] + type);
            }
        } else {
            for (int j = 0; j < nv; ++j) {
                int sv = ei[i + j], dv = ei[E + i + j];
                bb[j] = dv >> 7;
                cd[j] = ((unsigned)(2 * (dv & 127) + type) << 18)
                      | (unsigned)(2 * sv + type);
            }
        }
#pragma unroll
        for (int j = 0; j < 8; ++j)
            if (j < nv) rk[j] = atomicAdd(&histC[bb[j]], 1);
        __syncthreads();

        // exclusive scan of histC[0..nb): 2-elem pairing + Hillis on h2[0..P)
        if (t < P) {
            int a = histC[2 * t];
            int b2 = (2 * t + 1 < nb) ? histC[2 * t + 1] : 0;
            h2[t] = a + b2;
        }
        __syncthreads();
        for (int o = 1; o < P; o <<= 1) {
            int v = (t < P && t >= o) ? h2[t - o] : 0;
            __syncthreads();
            if (t < P) h2[t] += v;
            __syncthreads();
        }
        if (t < P) {
            int a = histC[2 * t];
            int b2 = (2 * t + 1 < nb) ? histC[2 * t + 1] : 0;
            int inc = h2[t];
            baseC[2 * t] = inc - a - b2;
            if (2 * t + 1 < nb) baseC[2 * t + 1] = inc - b2;
        }
        for (int b = t; b < nb; b += 512) gbC[b] = cur[b];   // cursor snapshot
        __syncthreads();

        // dense LDS scatter + precomputed global position
#pragma unroll
        for (int j = 0; j < 8; ++j)
            if (j < nv) {
                int p = baseC[bb[j]] + rk[j];
                stg[p] = cd[j];
                stg2[p] = (unsigned)(gbC[bb[j]] + rk[j]);
            }
        __syncthreads();

        // advance cursors + coalesced run-ordered flush
        for (int b = t; b < nb; b += 512) cur[b] = gbC[b] + histC[b];
        const int tot = min(PCH, e1 - c0);
        for (int j = t; j < tot; j += 512)
            codes[stg2[j]] = stg[j];
        __syncthreads();
    }
}

// ---------------- 2. dcxw: per-bucket degree count + fused W-projection --------
// bucket b covers vnodes [256b,256b+256) = nodes [128b,128b+128).
__global__ __launch_bounds__(256)
void dcxw_kernel(const unsigned int* __restrict__ codes, const int* __restrict__ goff,
                 const float* __restrict__ x,
                 const float* __restrict__ Wn, const float* __restrict__ Ws,
                 int* __restrict__ cnt, __half2* __restrict__ xws, int N, int M) {
    __shared__ float wtn[32 * 64];   // W^T: [h][k]
    __shared__ float wts[32 * 64];
    __shared__ int dcnt[BSZ];
    const int t = threadIdx.x;
    dcnt[t] = 0;
    for (int i = t; i < 64 * 32; i += 256) {
        int k = i >> 5, h = i & 31;
        wtn[h * 64 + k] = Wn[i];
        wts[h * 64 + k] = Ws[i];
    }
    __syncthreads();

    const int b = blockIdx.x;
    const int base = b * CAP2;
    const int end = base + goff[b];
    const int t0 = base + ((end - base) & ~3);
    for (int e = base + t * 4; e < t0; e += 256 * 4) {
        uint4 c = *(const uint4*)(codes + e);
        atomicAdd(&dcnt[c.x >> 18], 1);
        atomicAdd(&dcnt[c.y >> 18], 1);
        atomicAdd(&dcnt[c.z >> 18], 1);
        atomicAdd(&dcnt[c.w >> 18], 1);
    }
    if (t < end - t0) atomicAdd(&dcnt[codes[t0 + t] >> 18], 1);
    __syncthreads();

    const int vnode = b * BSZ + t;
    if (vnode < M) cnt[vnode] = dcnt[t];

    // xw: thread t -> node p = t>>1, output half = t&1 (s2 in [8h, 8h+8))
    const int p = t >> 1, half = t & 1;
    const int node = b * 128 + p;
    if (node >= N) return;

    float xr[64];
    const float4* x4 = (const float4*)(x + (size_t)node * 64);
#pragma unroll
    for (int q = 0; q < 16; ++q) {
        float4 v = x4[q];
        xr[4 * q] = v.x; xr[4 * q + 1] = v.y; xr[4 * q + 2] = v.z; xr[4 * q + 3] = v.w;
    }
    float dn = rsqrtf((float)dcnt[2 * p] + 1.0f);
    float ds = rsqrtf((float)dcnt[2 * p + 1] + 1.0f);

    unsigned pn[8], ps[8];
#pragma unroll
    for (int s2i = 0; s2i < 8; ++s2i) {
        const int s2 = half * 8 + s2i;
        float a0n = 0.f, a1n = 0.f, a0s = 0.f, a1s = 0.f;
#pragma unroll
        for (int q = 0; q < 16; ++q) {
            float4 w0n = *(const float4*)&wtn[(2 * s2) * 64 + 4 * q];
            float4 w1n = *(const float4*)&wtn[(2 * s2 + 1) * 64 + 4 * q];
            float4 w0s = *(const float4*)&wts[(2 * s2) * 64 + 4 * q];
            float4 w1s = *(const float4*)&wts[(2 * s2 + 1) * 64 + 4 * q];
            float x0 = xr[4 * q], x1 = xr[4 * q + 1], x2 = xr[4 * q + 2], x3 = xr[4 * q + 3];
            a0n += x0 * w0n.x + x1 * w0n.y + x2 * w0n.z + x3 * w0n.w;
            a1n += x0 * w1n.x + x1 * w1n.y + x2 * w1n.z + x3 * w1n.w;
            a0s += x0 * w0s.x + x1 * w0s.y + x2 * w0s.z + x3 * w0s.w;
            a1s += x0 * w1s.x + x1 * w1s.y + x2 * w1s.z + x3 * w1s.w;
        }
        __half2 hn = __floats2half2_rn(a0n * dn, a1n * dn);
        __half2 hs = __floats2half2_rn(a0s * ds, a1s * ds);
        pn[s2i] = *(unsigned*)&hn;
        ps[s2i] = *(unsigned*)&hs;
    }
    uint4* on = (uint4*)(xws + (size_t)(2 * node) * 16 + half * 8);
    uint4* os = (uint4*)(xws + (size_t)(2 * node + 1) * 16 + half * 8);
    on[0] = make_uint4(pn[0], pn[1], pn[2], pn[3]);
    on[1] = make_uint4(pn[4], pn[5], pn[6], pn[7]);
    os[0] = make_uint4(ps[0], ps[1], ps[2], ps[3]);
    os[1] = make_uint4(ps[4], ps[5], ps[6], ps[7]);
}

// ---------------- 3. gather: fixed-point LDS accumulate + fused epilogue -------
__global__ __launch_bounds__(512)
void gather_kernel(const unsigned int* __restrict__ codes, const int* __restrict__ goff,
                   const __half2* __restrict__ xws, const int* __restrict__ cnt,
                   const float* __restrict__ b_n, const float* __restrict__ b_s,
                   const float* __restrict__ W_lin, const float* __restrict__ b_lin,
                   float* __restrict__ out, int N) {
    __shared__ int facc[BSZ * LDSPAD];   // 33.8 KB
    for (int i = threadIdx.x; i < BSZ * LDSPAD; i += 512) facc[i] = 0;
    __syncthreads();
    const int b = blockIdx.x;
    const int base = b * CAP2;                  // multiple of 4
    const int end = base + goff[b];
    const int sl = threadIdx.x & 15;
    const int grp = threadIdx.x >> 4;           // 32 groups of 16 lanes

#define GA(cc) xws[(size_t)((cc) & 0x3FFFFu) * 16 + sl]
#define ACC_EDGE(cc, ww) do {                                                \
        float2 f_ = __half22float2(ww);                                      \
        int r_ = (int)((cc) >> 18) * LDSPAD + sl;                            \
        atomicAdd(&facc[r_],      __float2int_rn(f_.x * FXS));               \
        atomicAdd(&facc[r_ + 16], __float2int_rn(f_.y * FXS));               \
    } while (0)

    const int t0 = base + ((end - base) & ~15);
    for (int e = base + grp * 16; e < t0; e += 32 * 16) {
        uint4 c0 = *(const uint4*)(codes + e);
        uint4 c1 = *(const uint4*)(codes + e + 4);
        uint4 c2 = *(const uint4*)(codes + e + 8);
        uint4 c3 = *(const uint4*)(codes + e + 12);
        __half2 w0 = GA(c0.x), w1 = GA(c0.y), w2 = GA(c0.z), w3 = GA(c0.w);
        __half2 w4 = GA(c1.x), w5 = GA(c1.y), w6 = GA(c1.z), w7 = GA(c1.w);
        __half2 w8 = GA(c2.x), w9 = GA(c2.y), wA = GA(c2.z), wB = GA(c2.w);
        __half2 wC = GA(c3.x), wD = GA(c3.y), wE = GA(c3.z), wF = GA(c3.w);
        ACC_EDGE(c0.x, w0); ACC_EDGE(c0.y, w1); ACC_EDGE(c0.z, w2); ACC_EDGE(c0.w, w3);
        ACC_EDGE(c1.x, w4); ACC_EDGE(c1.y, w5); ACC_EDGE(c1.z, w6); ACC_EDGE(c1.w, w7);
        ACC_EDGE(c2.x, w8); ACC_EDGE(c2.y, w9); ACC_EDGE(c2.z, wA); ACC_EDGE(c2.w, wB);
        ACC_EDGE(c3.x, wC); ACC_EDGE(c3.y, wD); ACC_EDGE(c3.z, wE); ACC_EDGE(c3.w, wF);
    }
    for (int e = t0 + grp; e < end; e += 32) {
        unsigned c = codes[e];
        __half2 w = GA(c);
        ACC_EDGE(c, w);
    }
#undef ACC_EDGE
#undef GA

    __syncthreads();
    const float bn0 = b_n[2 * sl], bn1 = b_n[2 * sl + 1];
    const float bs0 = b_s[2 * sl], bs1 = b_s[2 * sl + 1];
    const float wl0 = W_lin[2 * sl], wl1 = W_lin[2 * sl + 1];
    const float bl  = b_lin[0];
    for (int p = grp; p < 128; p += 32) {
        int node = b * 128 + p;
        if (node >= N) break;
        int rn = (2 * p) * LDSPAD, rs = rn + LDSPAD;
        float anx = (float)facc[rn + sl] * FXSI, any_ = (float)facc[rn + 16 + sl] * FXSI;
        float asx = (float)facc[rs + sl] * FXSI, asy  = (float)facc[rs + 16 + sl] * FXSI;
        float2 ns = __half22float2(xws[(size_t)(2 * node) * 16 + sl]);
        float2 ss = __half22float2(xws[(size_t)(2 * node + 1) * 16 + sl]);
        float dn  = rsqrtf((float)cnt[2 * node] + 1.0f);
        float dsv = rsqrtf((float)cnt[2 * node + 1] + 1.0f);
        float h0 = (anx + ns.x) * dn + bn0 + (asx + ss.x) * dsv + bs0;
        float h1 = (any_ + ns.y) * dn + bn1 + (asy + ss.y) * dsv + bs1;
        float pr = fmaxf(h0, 0.f) * wl0 + fmaxf(h1, 0.f) * wl1;
#pragma unroll
        for (int off = 8; off > 0; off >>= 1) pr += __shfl_xor(pr, off, 16);
        if (sl == 0) out[node] = pr + bl;
    }
}

extern "C" void kernel_launch(void* const* d_in, const int* in_sizes, int n_in,
                              void* d_out, int out_size, void* d_ws, size_t ws_size,
                              hipStream_t stream) {
    const float* x     = (const float*)d_in[0];
    const int*   ei_n  = (const int*)d_in[1];
    const int*   ei_s  = (const int*)d_in[2];
    const float* W_n   = (const float*)d_in[3];
    const float* b_n   = (const float*)d_in[4];
    const float* W_s   = (const float*)d_in[5];
    const float* b_s   = (const float*)d_in[6];
    const float* W_lin = (const float*)d_in[7];
    const float* b_lin = (const float*)d_in[8];
    float* out = (float*)d_out;

    const int N  = in_sizes[0] / 64;   // 100000
    const int En = in_sizes[1] / 2;    // 3200000
    const int Es = in_sizes[2] / 2;    // 3200000
    const int M  = 2 * N;              // 200000 vnodes (vn = 2*node + type)
    const int nb = (M + BSZ - 1) / BSZ;            // 782 buckets

    // Workspace (~43 MB): goff[1024] | cnt[M] | codes[nb*CAP2] (16B aligned)
    // | xws[16*M half2]
    int* goff = (int*)d_ws;
    int* cnt  = goff + 1024;
    uintptr_t pc = (uintptr_t)(cnt + M);
    pc = (pc + 15) & ~(uintptr_t)15;
    unsigned int* codes = (unsigned int*)pc;
    __half2* xws = (__half2*)(codes + (size_t)nb * CAP2);

    hipMemsetAsync(goff, 0, (size_t)nb * sizeof(int), stream);

    place_kernel<<<dim3(SLICES, 2), 512, 0, stream>>>(ei_n, ei_s, goff, codes,
                                                      En, Es, nb);
    dcxw_kernel<<<nb, 256, 0, stream>>>(codes, goff, x, W_n, W_s, cnt, xws, N, M);
    gather_kernel<<<nb, 512, 0, stream>>>(codes, goff, xws, cnt,
                                          b_n, b_s, W_lin, b_lin, out, N);
}

// Round 9
// 292.150 us; speedup vs baseline: 1.2780x; 1.0061x over previous
//
#include <hip/hip_runtime.h>
#include <hip/hip_fp16.h>

// R20: attack the two helpers hiding under gather's 98us in top-5
// (total-gather=196us => place~90 + dcxw~85).
//  - place: Hillis scan (9 rounds x 2 barriers over 391 LDS ints, 75% lanes
//    idle) -> wave-structured shfl scan, 5 barriers/chunk instead of ~24.
//  - dcxw: was LDS-issue-bound (512 ds_read_b128/thread on the one-per-CU
//    LDS pipe ~12cyc each). Now thread=node, W^T pre-transposed to GLOBAL
//    ws by init kernel, read with wave-uniform addresses (scalarizable /
//    L1 broadcast). No W LDS staging. 2 buckets per block (391 blocks).
//  - init kernel replaces memset (zeroes goff + writes W^T).
// gather unchanged (98us @ FETCH 294MB = its structural floor for now).
//
// code = (dst_local<<18) | vsrc; dst_local = 2*(d&127)+type; vsrc = 2*s+type
// vnode = 2*node+type; bucket = vnode>>8 = d>>7 (type-free).

#define SLICES 256
#define BSZ    256            // vnodes per bucket (=128 node pairs)
#define NB_MAX 800
#define CAP2   9216           // words reserved per bucket (mult of 4)
#define PCH    4096           // place: edges per chunk (512 thr x 8)
#define LDSPAD 33
#define FXS    65536.0f
#define FXSI   (1.0f / 65536.0f)

// ---------------- 0. init: zero goff + transpose W into workspace ------------
__global__ __launch_bounds__(512)
void init_kernel(const float* __restrict__ Wn, const float* __restrict__ Ws,
                 int* __restrict__ goff, float* __restrict__ wtn,
                 float* __restrict__ wts, int nb) {
    const int t = threadIdx.x;
    for (int b = t; b < nb; b += 512) goff[b] = 0;
    for (int i = t; i < 64 * 32; i += 512) {
        int k = i >> 5, h = i & 31;
        wtn[h * 64 + k] = Wn[i];
        wts[h * 64 + k] = Ws[i];
    }
}

// ---------------- 1. place: 2-pass LDS radix, wave-shfl scan ------------------
__global__ __launch_bounds__(512)
void place_kernel(const int* __restrict__ ei_n, const int* __restrict__ ei_s,
                  int* __restrict__ goff, unsigned int* __restrict__ codes,
                  int En, int Es, int nb) {
    __shared__ unsigned stg[PCH];        // 16 KB
    __shared__ unsigned stg2[PCH];       // 16 KB global position per element
    __shared__ int histT[NB_MAX];        // slice-total hist
    __shared__ int cur[NB_MAX];          // running global cursors
    __shared__ int histC[NB_MAX];        // per-chunk hist
    __shared__ int baseC[NB_MAX];        // per-chunk stage base
    __shared__ int gbC[NB_MAX];          // per-chunk cursor snapshot
    __shared__ int wsum[8];
    const int t = threadIdx.x;
    const int wid = t >> 6, lane = t & 63;
    const int type = blockIdx.y;
    const int* __restrict__ ei = type ? ei_s : ei_n;
    const int E = type ? Es : En;
    int per = ((E + SLICES - 1) / SLICES + 7) & ~7;
    const int e0 = blockIdx.x * per;
    const int e1 = min(e0 + per, E);

    for (int b = t; b < nb; b += 512) histT[b] = 0;
    __syncthreads();

    // ---- pass A: slice-total histogram (dst stream only, no inner barriers)
    for (int c0 = e0; c0 < e1; c0 += PCH) {
        const int i = c0 + t * 8;
        int nv = e1 - i; nv = nv < 0 ? 0 : (nv > 8 ? 8 : nv);
        if (nv == 8) {
            int4 dA = *(const int4*)(ei + E + i), dB = *(const int4*)(ei + E + i + 4);
            atomicAdd(&histT[dA.x >> 7], 1);
            atomicAdd(&histT[dA.y >> 7], 1);
            atomicAdd(&histT[dA.z >> 7], 1);
            atomicAdd(&histT[dA.w >> 7], 1);
            atomicAdd(&histT[dB.x >> 7], 1);
            atomicAdd(&histT[dB.y >> 7], 1);
            atomicAdd(&histT[dB.z >> 7], 1);
            atomicAdd(&histT[dB.w >> 7], 1);
        } else {
            for (int j = 0; j < nv; ++j) atomicAdd(&histT[ei[E + i + j] >> 7], 1);
        }
    }
    __syncthreads();

    // ---- single global reservation per block
    for (int b = t; b < nb; b += 512) {
        int c = histT[b];
        cur[b] = b * CAP2 + (c ? atomicAdd(&goff[b], c) : 0);
    }
    for (int b = t; b < nb; b += 512) histC[b] = 0;
    __syncthreads();

    // ---- pass B: per-chunk rank + wave-scan + stage + coalesced flush
    for (int c0 = e0; c0 < e1; c0 += PCH) {
        const int i = c0 + t * 8;
        int nv = e1 - i; nv = nv < 0 ? 0 : (nv > 8 ? 8 : nv);
        unsigned cd[8]; int bb[8], rk[8];
        if (nv == 8) {
            int4 sA = *(const int4*)(ei + i),     sB = *(const int4*)(ei + i + 4);
            int4 dA = *(const int4*)(ei + E + i), dB = *(const int4*)(ei + E + i + 4);
            int ss[8] = {sA.x, sA.y, sA.z, sA.w, sB.x, sB.y, sB.z, sB.w};
            int dd[8] = {dA.x, dA.y, dA.z, dA.w, dB.x, dB.y, dB.z, dB.w};
#pragma unroll
            for (int j = 0; j < 8; ++j) {
                bb[j] = dd[j] >> 7;
                cd[j] = ((unsigned)(2 * (dd[j] & 127) + type) << 18)
                      | (unsigned)(2 * ss[j] + type);
            }
        } else {
            for (int j = 0; j < nv; ++j) {
                int sv = ei[i + j], dv = ei[E + i + j];
                bb[j] = dv >> 7;
                cd[j] = ((unsigned)(2 * (dv & 127) + type) << 18)
                      | (unsigned)(2 * sv + type);
            }
        }
#pragma unroll
        for (int j = 0; j < 8; ++j)
            if (j < nv) rk[j] = atomicAdd(&histC[bb[j]], 1);
        __syncthreads();                               // B: histC final

        // wave-structured exclusive scan: wave w covers [128w, 128w+128)
        const int i0 = wid * 128 + lane, i1 = i0 + 64;
        int v0 = (i0 < nb) ? histC[i0] : 0;
        int v1 = (i1 < nb) ? histC[i1] : 0;
        int x0 = v0;
#pragma unroll
        for (int o = 1; o < 64; o <<= 1) { int n = __shfl_up(x0, o, 64); if (lane >= o) x0 += n; }
        int tot0 = __shfl(x0, 63, 64);
        int x1 = v1;
#pragma unroll
        for (int o = 1; o < 64; o <<= 1) { int n = __shfl_up(x1, o, 64); if (lane >= o) x1 += n; }
        int tot1 = __shfl(x1, 63, 64);
        if (lane == 0) wsum[wid] = tot0 + tot1;
        // cursor snapshot + advance (each b owned by one thread)
        for (int b = t; b < nb; b += 512) {
            int c = histC[b], g = cur[b];
            gbC[b] = g;
            cur[b] = g + c;
        }
        __syncthreads();                               // C: wsum, gbC ready
        int woff = 0;
#pragma unroll
        for (int k = 0; k < 8; ++k) woff += (k < wid) ? wsum[k] : 0;
        if (i0 < nb) baseC[i0] = woff + (x0 - v0);
        if (i1 < nb) baseC[i1] = woff + tot0 + (x1 - v1);
        __syncthreads();                               // D: baseC ready

        // dense LDS scatter + precomputed global position
#pragma unroll
        for (int j = 0; j < 8; ++j)
            if (j < nv) {
                int p = baseC[bb[j]] + rk[j];
                stg[p] = cd[j];
                stg2[p] = (unsigned)(gbC[bb[j]] + rk[j]);
            }
        __syncthreads();                               // E: stage ready

        // coalesced run-ordered flush + zero histC for next chunk
        const int tot = min(PCH, e1 - c0);
        for (int j = t; j < tot; j += 512)
            codes[stg2[j]] = stg[j];
        for (int b = t; b < nb; b += 512) histC[b] = 0;
        __syncthreads();                               // F
    }
}

// ---------------- 2. dcxw: 2 buckets/block, thread=node, global-W^T xw --------
// block B covers buckets 2B,2B+1 = vnodes [512B,512B+512) = nodes [256B,256B+256)
__global__ __launch_bounds__(256)
void dcxw_kernel(const unsigned int* __restrict__ codes, const int* __restrict__ goff,
                 const float* __restrict__ x,
                 const float* __restrict__ wtn, const float* __restrict__ wts,
                 int* __restrict__ cnt, __half2* __restrict__ xws, int N, int M, int nb) {
    __shared__ int dcnt[512];
    const int t = threadIdx.x;
    dcnt[t] = 0;
    dcnt[t + 256] = 0;
    __syncthreads();

    for (int bb = 0; bb < 2; ++bb) {
        const int bidx = 2 * blockIdx.x + bb;
        if (bidx >= nb) break;
        const int off = bb << 8;
        const int base = bidx * CAP2;
        const int end = base + goff[bidx];
        const int t0 = base + ((end - base) & ~3);
        for (int e = base + t * 4; e < t0; e += 256 * 4) {
            uint4 c = *(const uint4*)(codes + e);
            atomicAdd(&dcnt[off + (c.x >> 18)], 1);
            atomicAdd(&dcnt[off + (c.y >> 18)], 1);
            atomicAdd(&dcnt[off + (c.z >> 18)], 1);
            atomicAdd(&dcnt[off + (c.w >> 18)], 1);
        }
        if (t < end - t0) atomicAdd(&dcnt[off + (codes[t0 + t] >> 18)], 1);
    }
    __syncthreads();

    const int v0 = blockIdx.x * 512 + t;
    if (v0 < M) cnt[v0] = dcnt[t];
    const int v1 = v0 + 256;
    if (v1 < M) cnt[v1] = dcnt[t + 256];

    const int node = blockIdx.x * 256 + t;
    if (node >= N) return;

    float xr[64];
    const float4* x4 = (const float4*)(x + (size_t)node * 64);
#pragma unroll
    for (int q = 0; q < 16; ++q) {
        float4 v = x4[q];
        xr[4 * q] = v.x; xr[4 * q + 1] = v.y; xr[4 * q + 2] = v.z; xr[4 * q + 3] = v.w;
    }
    float dn = rsqrtf((float)dcnt[2 * t] + 1.0f);
    float ds = rsqrtf((float)dcnt[2 * t + 1] + 1.0f);

    const float4* wn4 = (const float4*)wtn;   // wtn[h*64+k] -> wn4[h*16+q]
    const float4* ws4 = (const float4*)wts;

    unsigned pn[16], ps[16];
#pragma unroll
    for (int s2 = 0; s2 < 16; ++s2) {
        float a0n = 0.f, a1n = 0.f, a0s = 0.f, a1s = 0.f;
#pragma unroll
        for (int q = 0; q < 16; ++q) {
            // wave-uniform addresses -> scalar / L1-broadcast loads
            float4 w0n = wn4[(2 * s2) * 16 + q];
            float4 w1n = wn4[(2 * s2 + 1) * 16 + q];
            float4 w0s = ws4[(2 * s2) * 16 + q];
            float4 w1s = ws4[(2 * s2 + 1) * 16 + q];
            float x0 = xr[4 * q], x1 = xr[4 * q + 1], x2 = xr[4 * q + 2], x3 = xr[4 * q + 3];
            a0n += x0 * w0n.x + x1 * w0n.y + x2 * w0n.z + x3 * w0n.w;
            a1n += x0 * w1n.x + x1 * w1n.y + x2 * w1n.z + x3 * w1n.w;
            a0s += x0 * w0s.x + x1 * w0s.y + x2 * w0s.z + x3 * w0s.w;
            a1s += x0 * w1s.x + x1 * w1s.y + x2 * w1s.z + x3 * w1s.w;
        }
        __half2 hn = __floats2half2_rn(a0n * dn, a1n * dn);
        __half2 hs = __floats2half2_rn(a0s * ds, a1s * ds);
        pn[s2] = *(unsigned*)&hn;
        ps[s2] = *(unsigned*)&hs;
    }
    uint4* on = (uint4*)(xws + (size_t)(2 * node) * 16);
    uint4* os = (uint4*)(xws + (size_t)(2 * node + 1) * 16);
#pragma unroll
    for (int q = 0; q < 4; ++q) {
        on[q] = make_uint4(pn[4 * q], pn[4 * q + 1], pn[4 * q + 2], pn[4 * q + 3]);
        os[q] = make_uint4(ps[4 * q], ps[4 * q + 1], ps[4 * q + 2], ps[4 * q + 3]);
    }
}

// ---------------- 3. gather: fixed-point LDS accumulate + fused epilogue -------
__global__ __launch_bounds__(512)
void gather_kernel(const unsigned int* __restrict__ codes, const int* __restrict__ goff,
                   const __half2* __restrict__ xws, const int* __restrict__ cnt,
                   const float* __restrict__ b_n, const float* __restrict__ b_s,
                   const float* __restrict__ W_lin, const float* __restrict__ b_lin,
                   float* __restrict__ out, int N) {
    __shared__ int facc[BSZ * LDSPAD];   // 33.8 KB
    for (int i = threadIdx.x; i < BSZ * LDSPAD; i += 512) facc[i] = 0;
    __syncthreads();
    const int b = blockIdx.x;
    const int base = b * CAP2;                  // multiple of 4
    const int end = base + goff[b];
    const int sl = threadIdx.x & 15;
    const int grp = threadIdx.x >> 4;           // 32 groups of 16 lanes

#define GA(cc) xws[(size_t)((cc) & 0x3FFFFu) * 16 + sl]
#define ACC_EDGE(cc, ww) do {                                                \
        float2 f_ = __half22float2(ww);                                      \
        int r_ = (int)((cc) >> 18) * LDSPAD + sl;                            \
        atomicAdd(&facc[r_],      __float2int_rn(f_.x * FXS));               \
        atomicAdd(&facc[r_ + 16], __float2int_rn(f_.y * FXS));               \
    } while (0)

    const int t0 = base + ((end - base) & ~15);
    for (int e = base + grp * 16; e < t0; e += 32 * 16) {
        uint4 c0 = *(const uint4*)(codes + e);
        uint4 c1 = *(const uint4*)(codes + e + 4);
        uint4 c2 = *(const uint4*)(codes + e + 8);
        uint4 c3 = *(const uint4*)(codes + e + 12);
        __half2 w0 = GA(c0.x), w1 = GA(c0.y), w2 = GA(c0.z), w3 = GA(c0.w);
        __half2 w4 = GA(c1.x), w5 = GA(c1.y), w6 = GA(c1.z), w7 = GA(c1.w);
        __half2 w8 = GA(c2.x), w9 = GA(c2.y), wA = GA(c2.z), wB = GA(c2.w);
        __half2 wC = GA(c3.x), wD = GA(c3.y), wE = GA(c3.z), wF = GA(c3.w);
        ACC_EDGE(c0.x, w0); ACC_EDGE(c0.y, w1); ACC_EDGE(c0.z, w2); ACC_EDGE(c0.w, w3);
        ACC_EDGE(c1.x, w4); ACC_EDGE(c1.y, w5); ACC_EDGE(c1.z, w6); ACC_EDGE(c1.w, w7);
        ACC_EDGE(c2.x, w8); ACC_EDGE(c2.y, w9); ACC_EDGE(c2.z, wA); ACC_EDGE(c2.w, wB);
        ACC_EDGE(c3.x, wC); ACC_EDGE(c3.y, wD); ACC_EDGE(c3.z, wE); ACC_EDGE(c3.w, wF);
    }
    for (int e = t0 + grp; e < end; e += 32) {
        unsigned c = codes[e];
        __half2 w = GA(c);
        ACC_EDGE(c, w);
    }
#undef ACC_EDGE
#undef GA

    __syncthreads();
    const float bn0 = b_n[2 * sl], bn1 = b_n[2 * sl + 1];
    const float bs0 = b_s[2 * sl], bs1 = b_s[2 * sl + 1];
    const float wl0 = W_lin[2 * sl], wl1 = W_lin[2 * sl + 1];
    const float bl  = b_lin[0];
    for (int p = grp; p < 128; p += 32) {
        int node = b * 128 + p;
        if (node >= N) break;
        int rn = (2 * p) * LDSPAD, rs = rn + LDSPAD;
        float anx = (float)facc[rn + sl] * FXSI, any_ = (float)facc[rn + 16 + sl] * FXSI;
        float asx = (float)facc[rs + sl] * FXSI, asy  = (float)facc[rs + 16 + sl] * FXSI;
        float2 ns = __half22float2(xws[(size_t)(2 * node) * 16 + sl]);
        float2 ss = __half22float2(xws[(size_t)(2 * node + 1) * 16 + sl]);
        float dn  = rsqrtf((float)cnt[2 * node] + 1.0f);
        float dsv = rsqrtf((float)cnt[2 * node + 1] + 1.0f);
        float h0 = (anx + ns.x) * dn + bn0 + (asx + ss.x) * dsv + bs0;
        float h1 = (any_ + ns.y) * dn + bn1 + (asy + ss.y) * dsv + bs1;
        float pr = fmaxf(h0, 0.f) * wl0 + fmaxf(h1, 0.f) * wl1;
#pragma unroll
        for (int off = 8; off > 0; off >>= 1) pr += __shfl_xor(pr, off, 16);
        if (sl == 0) out[node] = pr + bl;
    }
}

extern "C" void kernel_launch(void* const* d_in, const int* in_sizes, int n_in,
                              void* d_out, int out_size, void* d_ws, size_t ws_size,
                              hipStream_t stream) {
    const float* x     = (const float*)d_in[0];
    const int*   ei_n  = (const int*)d_in[1];
    const int*   ei_s  = (const int*)d_in[2];
    const float* W_n   = (const float*)d_in[3];
    const float* b_n   = (const float*)d_in[4];
    const float* W_s   = (const float*)d_in[5];
    const float* b_s   = (const float*)d_in[6];
    const float* W_lin = (const float*)d_in[7];
    const float* b_lin = (const float*)d_in[8];
    float* out = (float*)d_out;

    const int N  = in_sizes[0] / 64;   // 100000
    const int En = in_sizes[1] / 2;    // 3200000
    const int Es = in_sizes[2] / 2;    // 3200000
    const int M  = 2 * N;              // 200000 vnodes (vn = 2*node + type)
    const int nb = (M + BSZ - 1) / BSZ;            // 782 buckets

    // Workspace (~43 MB): goff[1024] | cnt[M] | wtn[2048] | wts[2048]
    // | codes[nb*CAP2] (16B aligned) | xws[16*M half2]
    int*   goff = (int*)d_ws;
    int*   cnt  = goff + 1024;
    float* wtn  = (float*)(cnt + M);
    float* wts  = wtn + 2048;
    uintptr_t pc = (uintptr_t)(wts + 2048);
    pc = (pc + 15) & ~(uintptr_t)15;
    unsigned int* codes = (unsigned int*)pc;
    __half2* xws = (__half2*)(codes + (size_t)nb * CAP2);

    init_kernel<<<1, 512, 0, stream>>>(W_n, W_s, goff, wtn, wts, nb);
    place_kernel<<<dim3(SLICES, 2), 512, 0, stream>>>(ei_n, ei_s, goff, codes,
                                                      En, Es, nb);
    dcxw_kernel<<<(nb + 1) / 2, 256, 0, stream>>>(codes, goff, x, wtn, wts,
                                                  cnt, xws, N, M, nb);
    gather_kernel<<<nb, 512, 0, stream>>>(codes, goff, xws, cnt,
                                          b_n, b_s, W_lin, b_lin, out, N);
}

// Round 11
// 287.597 us; speedup vs baseline: 1.2982x; 1.0158x over previous
//
#include <hip/hip_runtime.h>
#include <hip/hip_fp16.h>

// R22: revert to proven R20 multi-dispatch pipeline (292us; R21's cooperative
// mega-kernel silently failed to launch under graph capture -> zero output).
// Change vs R20: gather at 1024 threads/block (64 sixteen-lane groups).
// Rationale: gather showed Occupancy 49% with LDS/VGPR allowing far more --
// grid shape (782x512, ~24 waves/CU with tail) under-fills the CUs. 16
// waves/block x 2 blocks/CU = 32 waves = 100% cap, 2x outstanding random
// 64B gathers. place/dcxw/init unchanged.
//
// code = (dst_local<<18) | vsrc; dst_local = 2*(d&127)+type; vsrc = 2*s+type
// vnode = 2*node+type; bucket = vnode>>8 = d>>7 (type-free).

#define SLICES 256
#define BSZ    256            // vnodes per bucket (=128 node pairs)
#define NB_MAX 800
#define CAP2   9216           // words reserved per bucket (mult of 4)
#define PCH    4096           // place: edges per chunk (512 thr x 8)
#define LDSPAD 33
#define FXS    65536.0f
#define FXSI   (1.0f / 65536.0f)

// ---------------- 0. init: zero goff + transpose W into workspace ------------
__global__ __launch_bounds__(512)
void init_kernel(const float* __restrict__ Wn, const float* __restrict__ Ws,
                 int* __restrict__ goff, float* __restrict__ wtn,
                 float* __restrict__ wts, int nb) {
    const int t = threadIdx.x;
    for (int b = t; b < nb; b += 512) goff[b] = 0;
    for (int i = t; i < 64 * 32; i += 512) {
        int k = i >> 5, h = i & 31;
        wtn[h * 64 + k] = Wn[i];
        wts[h * 64 + k] = Ws[i];
    }
}

// ---------------- 1. place: 2-pass LDS radix, wave-shfl scan ------------------
__global__ __launch_bounds__(512)
void place_kernel(const int* __restrict__ ei_n, const int* __restrict__ ei_s,
                  int* __restrict__ goff, unsigned int* __restrict__ codes,
                  int En, int Es, int nb) {
    __shared__ unsigned stg[PCH];        // 16 KB
    __shared__ unsigned stg2[PCH];       // 16 KB global position per element
    __shared__ int histT[NB_MAX];        // slice-total hist
    __shared__ int cur[NB_MAX];          // running global cursors
    __shared__ int histC[NB_MAX];        // per-chunk hist
    __shared__ int baseC[NB_MAX];        // per-chunk stage base
    __shared__ int gbC[NB_MAX];          // per-chunk cursor snapshot
    __shared__ int wsum[8];
    const int t = threadIdx.x;
    const int wid = t >> 6, lane = t & 63;
    const int type = blockIdx.y;
    const int* __restrict__ ei = type ? ei_s : ei_n;
    const int E = type ? Es : En;
    int per = ((E + SLICES - 1) / SLICES + 7) & ~7;
    const int e0 = blockIdx.x * per;
    const int e1 = min(e0 + per, E);

    for (int b = t; b < nb; b += 512) histT[b] = 0;
    __syncthreads();

    // ---- pass A: slice-total histogram (dst stream only, no inner barriers)
    for (int c0 = e0; c0 < e1; c0 += PCH) {
        const int i = c0 + t * 8;
        int nv = e1 - i; nv = nv < 0 ? 0 : (nv > 8 ? 8 : nv);
        if (nv == 8) {
            int4 dA = *(const int4*)(ei + E + i), dB = *(const int4*)(ei + E + i + 4);
            atomicAdd(&histT[dA.x >> 7], 1);
            atomicAdd(&histT[dA.y >> 7], 1);
            atomicAdd(&histT[dA.z >> 7], 1);
            atomicAdd(&histT[dA.w >> 7], 1);
            atomicAdd(&histT[dB.x >> 7], 1);
            atomicAdd(&histT[dB.y >> 7], 1);
            atomicAdd(&histT[dB.z >> 7], 1);
            atomicAdd(&histT[dB.w >> 7], 1);
        } else {
            for (int j = 0; j < nv; ++j) atomicAdd(&histT[ei[E + i + j] >> 7], 1);
        }
    }
    __syncthreads();

    // ---- single global reservation per block
    for (int b = t; b < nb; b += 512) {
        int c = histT[b];
        cur[b] = b * CAP2 + (c ? atomicAdd(&goff[b], c) : 0);
    }
    for (int b = t; b < nb; b += 512) histC[b] = 0;
    __syncthreads();

    // ---- pass B: per-chunk rank + wave-scan + stage + coalesced flush
    for (int c0 = e0; c0 < e1; c0 += PCH) {
        const int i = c0 + t * 8;
        int nv = e1 - i; nv = nv < 0 ? 0 : (nv > 8 ? 8 : nv);
        unsigned cd[8]; int bb[8], rk[8];
        if (nv == 8) {
            int4 sA = *(const int4*)(ei + i),     sB = *(const int4*)(ei + i + 4);
            int4 dA = *(const int4*)(ei + E + i), dB = *(const int4*)(ei + E + i + 4);
            int ss[8] = {sA.x, sA.y, sA.z, sA.w, sB.x, sB.y, sB.z, sB.w};
            int dd[8] = {dA.x, dA.y, dA.z, dA.w, dB.x, dB.y, dB.z, dB.w};
#pragma unroll
            for (int j = 0; j < 8; ++j) {
                bb[j] = dd[j] >> 7;
                cd[j] = ((unsigned)(2 * (dd[j] & 127) + type) << 18)
                      | (unsigned)(2 * ss[j] + type);
            }
        } else {
            for (int j = 0; j < nv; ++j) {
                int sv = ei[i + j], dv = ei[E + i + j];
                bb[j] = dv >> 7;
                cd[j] = ((unsigned)(2 * (dv & 127) + type) << 18)
                      | (unsigned)(2 * sv + type);
            }
        }
#pragma unroll
        for (int j = 0; j < 8; ++j)
            if (j < nv) rk[j] = atomicAdd(&histC[bb[j]], 1);
        __syncthreads();                               // histC final

        // wave-structured exclusive scan: wave w covers [128w, 128w+128)
        const int i0 = wid * 128 + lane, i1 = i0 + 64;
        int v0 = (i0 < nb) ? histC[i0] : 0;
        int v1 = (i1 < nb) ? histC[i1] : 0;
        int x0 = v0;
#pragma unroll
        for (int o = 1; o < 64; o <<= 1) { int n = __shfl_up(x0, o, 64); if (lane >= o) x0 += n; }
        int tot0 = __shfl(x0, 63, 64);
        int x1 = v1;
#pragma unroll
        for (int o = 1; o < 64; o <<= 1) { int n = __shfl_up(x1, o, 64); if (lane >= o) x1 += n; }
        int tot1 = __shfl(x1, 63, 64);
        if (lane == 0) wsum[wid] = tot0 + tot1;
        // cursor snapshot + advance (each b owned by one thread)
        for (int b = t; b < nb; b += 512) {
            int c = histC[b], g = cur[b];
            gbC[b] = g;
            cur[b] = g + c;
        }
        __syncthreads();                               // wsum, gbC ready
        int woff = 0;
#pragma unroll
        for (int k = 0; k < 8; ++k) woff += (k < wid) ? wsum[k] : 0;
        if (i0 < nb) baseC[i0] = woff + (x0 - v0);
        if (i1 < nb) baseC[i1] = woff + tot0 + (x1 - v1);
        __syncthreads();                               // baseC ready

        // dense LDS scatter + precomputed global position
#pragma unroll
        for (int j = 0; j < 8; ++j)
            if (j < nv) {
                int p = baseC[bb[j]] + rk[j];
                stg[p] = cd[j];
                stg2[p] = (unsigned)(gbC[bb[j]] + rk[j]);
            }
        __syncthreads();                               // stage ready

        // coalesced run-ordered flush + zero histC for next chunk
        const int tot = min(PCH, e1 - c0);
        for (int j = t; j < tot; j += 512)
            codes[stg2[j]] = stg[j];
        for (int b = t; b < nb; b += 512) histC[b] = 0;
        __syncthreads();
    }
}

// ---------------- 2. dcxw: 2 buckets/block, thread=node, global-W^T xw --------
// block B covers buckets 2B,2B+1 = vnodes [512B,512B+512) = nodes [256B,256B+256)
__global__ __launch_bounds__(256)
void dcxw_kernel(const unsigned int* __restrict__ codes, const int* __restrict__ goff,
                 const float* __restrict__ x,
                 const float* __restrict__ wtn, const float* __restrict__ wts,
                 int* __restrict__ cnt, __half2* __restrict__ xws, int N, int M, int nb) {
    __shared__ int dcnt[512];
    const int t = threadIdx.x;
    dcnt[t] = 0;
    dcnt[t + 256] = 0;
    __syncthreads();

    for (int bb = 0; bb < 2; ++bb) {
        const int bidx = 2 * blockIdx.x + bb;
        if (bidx >= nb) break;
        const int off = bb << 8;
        const int base = bidx * CAP2;
        const int end = base + goff[bidx];
        const int t0 = base + ((end - base) & ~3);
        for (int e = base + t * 4; e < t0; e += 256 * 4) {
            uint4 c = *(const uint4*)(codes + e);
            atomicAdd(&dcnt[off + (c.x >> 18)], 1);
            atomicAdd(&dcnt[off + (c.y >> 18)], 1);
            atomicAdd(&dcnt[off + (c.z >> 18)], 1);
            atomicAdd(&dcnt[off + (c.w >> 18)], 1);
        }
        if (t < end - t0) atomicAdd(&dcnt[off + (codes[t0 + t] >> 18)], 1);
    }
    __syncthreads();

    const int v0 = blockIdx.x * 512 + t;
    if (v0 < M) cnt[v0] = dcnt[t];
    const int v1 = v0 + 256;
    if (v1 < M) cnt[v1] = dcnt[t + 256];

    const int node = blockIdx.x * 256 + t;
    if (node >= N) return;

    float xr[64];
    const float4* x4 = (const float4*)(x + (size_t)node * 64);
#pragma unroll
    for (int q = 0; q < 16; ++q) {
        float4 v = x4[q];
        xr[4 * q] = v.x; xr[4 * q + 1] = v.y; xr[4 * q + 2] = v.z; xr[4 * q + 3] = v.w;
    }
    float dn = rsqrtf((float)dcnt[2 * t] + 1.0f);
    float ds = rsqrtf((float)dcnt[2 * t + 1] + 1.0f);

    const float4* wn4 = (const float4*)wtn;   // wtn[h*64+k] -> wn4[h*16+q]
    const float4* ws4 = (const float4*)wts;

    unsigned pn[16], ps[16];
#pragma unroll
    for (int s2 = 0; s2 < 16; ++s2) {
        float a0n = 0.f, a1n = 0.f, a0s = 0.f, a1s = 0.f;
#pragma unroll
        for (int q = 0; q < 16; ++q) {
            // wave-uniform addresses -> scalar / L1-broadcast loads
            float4 w0n = wn4[(2 * s2) * 16 + q];
            float4 w1n = wn4[(2 * s2 + 1) * 16 + q];
            float4 w0s = ws4[(2 * s2) * 16 + q];
            float4 w1s = ws4[(2 * s2 + 1) * 16 + q];
            float x0 = xr[4 * q], x1 = xr[4 * q + 1], x2 = xr[4 * q + 2], x3 = xr[4 * q + 3];
            a0n += x0 * w0n.x + x1 * w0n.y + x2 * w0n.z + x3 * w0n.w;
            a1n += x0 * w1n.x + x1 * w1n.y + x2 * w1n.z + x3 * w1n.w;
            a0s += x0 * w0s.x + x1 * w0s.y + x2 * w0s.z + x3 * w0s.w;
            a1s += x0 * w1s.x + x1 * w1s.y + x2 * w1s.z + x3 * w1s.w;
        }
        __half2 hn = __floats2half2_rn(a0n * dn, a1n * dn);
        __half2 hs = __floats2half2_rn(a0s * ds, a1s * ds);
        pn[s2] = *(unsigned*)&hn;
        ps[s2] = *(unsigned*)&hs;
    }
    uint4* on = (uint4*)(xws + (size_t)(2 * node) * 16);
    uint4* os = (uint4*)(xws + (size_t)(2 * node + 1) * 16);
#pragma unroll
    for (int q = 0; q < 4; ++q) {
        on[q] = make_uint4(pn[4 * q], pn[4 * q + 1], pn[4 * q + 2], pn[4 * q + 3]);
        os[q] = make_uint4(ps[4 * q], ps[4 * q + 1], ps[4 * q + 2], ps[4 * q + 3]);
    }
}

// ---------------- 3. gather: 1024 threads, fixed-point LDS acc + epilogue -----
__global__ __launch_bounds__(1024)
void gather_kernel(const unsigned int* __restrict__ codes, const int* __restrict__ goff,
                   const __half2* __restrict__ xws, const int* __restrict__ cnt,
                   const float* __restrict__ b_n, const float* __restrict__ b_s,
                   const float* __restrict__ W_lin, const float* __restrict__ b_lin,
                   float* __restrict__ out, int N) {
    __shared__ int facc[BSZ * LDSPAD];   // 33.8 KB -> 2 blocks/CU (wave-capped)
    for (int i = threadIdx.x; i < BSZ * LDSPAD; i += 1024) facc[i] = 0;
    __syncthreads();
    const int b = blockIdx.x;
    const int base = b * CAP2;                  // multiple of 4
    const int end = base + goff[b];
    const int sl = threadIdx.x & 15;
    const int grp = threadIdx.x >> 4;           // 64 groups of 16 lanes

#define GA(cc) xws[(size_t)((cc) & 0x3FFFFu) * 16 + sl]
#define ACC_EDGE(cc, ww) do {                                                \
        float2 f_ = __half22float2(ww);                                      \
        int r_ = (int)((cc) >> 18) * LDSPAD + sl;                            \
        atomicAdd(&facc[r_],      __float2int_rn(f_.x * FXS));               \
        atomicAdd(&facc[r_ + 16], __float2int_rn(f_.y * FXS));               \
    } while (0)

    const int t0 = base + ((end - base) & ~15);
    for (int e = base + grp * 16; e < t0; e += 64 * 16) {
        uint4 c0 = *(const uint4*)(codes + e);
        uint4 c1 = *(const uint4*)(codes + e + 4);
        uint4 c2 = *(const uint4*)(codes + e + 8);
        uint4 c3 = *(const uint4*)(codes + e + 12);
        __half2 w0 = GA(c0.x), w1 = GA(c0.y), w2 = GA(c0.z), w3 = GA(c0.w);
        __half2 w4 = GA(c1.x), w5 = GA(c1.y), w6 = GA(c1.z), w7 = GA(c1.w);
        __half2 w8 = GA(c2.x), w9 = GA(c2.y), wA = GA(c2.z), wB = GA(c2.w);
        __half2 wC = GA(c3.x), wD = GA(c3.y), wE = GA(c3.z), wF = GA(c3.w);
        ACC_EDGE(c0.x, w0); ACC_EDGE(c0.y, w1); ACC_EDGE(c0.z, w2); ACC_EDGE(c0.w, w3);
        ACC_EDGE(c1.x, w4); ACC_EDGE(c1.y, w5); ACC_EDGE(c1.z, w6); ACC_EDGE(c1.w, w7);
        ACC_EDGE(c2.x, w8); ACC_EDGE(c2.y, w9); ACC_EDGE(c2.z, wA); ACC_EDGE(c2.w, wB);
        ACC_EDGE(c3.x, wC); ACC_EDGE(c3.y, wD); ACC_EDGE(c3.z, wE); ACC_EDGE(c3.w, wF);
    }
    for (int e = t0 + grp; e < end; e += 64) {
        unsigned c = codes[e];
        __half2 w = GA(c);
        ACC_EDGE(c, w);
    }
#undef ACC_EDGE
#undef GA

    __syncthreads();
    const float bn0 = b_n[2 * sl], bn1 = b_n[2 * sl + 1];
    const float bs0 = b_s[2 * sl], bs1 = b_s[2 * sl + 1];
    const float wl0 = W_lin[2 * sl], wl1 = W_lin[2 * sl + 1];
    const float bl  = b_lin[0];
    for (int p = grp; p < 128; p += 64) {
        int node = b * 128 + p;
        if (node >= N) break;
        int rn = (2 * p) * LDSPAD, rs = rn + LDSPAD;
        float anx = (float)facc[rn + sl] * FXSI, any_ = (float)facc[rn + 16 + sl] * FXSI;
        float asx = (float)facc[rs + sl] * FXSI, asy  = (float)facc[rs + 16 + sl] * FXSI;
        float2 ns = __half22float2(xws[(size_t)(2 * node) * 16 + sl]);
        float2 ss = __half22float2(xws[(size_t)(2 * node + 1) * 16 + sl]);
        float dn  = rsqrtf((float)cnt[2 * node] + 1.0f);
        float dsv = rsqrtf((float)cnt[2 * node + 1] + 1.0f);
        float h0 = (anx + ns.x) * dn + bn0 + (asx + ss.x) * dsv + bs0;
        float h1 = (any_ + ns.y) * dn + bn1 + (asy + ss.y) * dsv + bs1;
        float pr = fmaxf(h0, 0.f) * wl0 + fmaxf(h1, 0.f) * wl1;
#pragma unroll
        for (int off = 8; off > 0; off >>= 1) pr += __shfl_xor(pr, off, 16);
        if (sl == 0) out[node] = pr + bl;
    }
}

extern "C" void kernel_launch(void* const* d_in, const int* in_sizes, int n_in,
                              void* d_out, int out_size, void* d_ws, size_t ws_size,
                              hipStream_t stream) {
    const float* x     = (const float*)d_in[0];
    const int*   ei_n  = (const int*)d_in[1];
    const int*   ei_s  = (const int*)d_in[2];
    const float* W_n   = (const float*)d_in[3];
    const float* b_n   = (const float*)d_in[4];
    const float* W_s   = (const float*)d_in[5];
    const float* b_s   = (const float*)d_in[6];
    const float* W_lin = (const float*)d_in[7];
    const float* b_lin = (const float*)d_in[8];
    float* out = (float*)d_out;

    const int N  = in_sizes[0] / 64;   // 100000
    const int En = in_sizes[1] / 2;    // 3200000
    const int Es = in_sizes[2] / 2;    // 3200000
    const int M  = 2 * N;              // 200000 vnodes (vn = 2*node + type)
    const int nb = (M + BSZ - 1) / BSZ;            // 782 buckets

    // Workspace (~43 MB): goff[1024] | cnt[M] | wtn[2048] | wts[2048]
    // | codes[nb*CAP2] (16B aligned) | xws[16*M half2]
    int*   goff = (int*)d_ws;
    int*   cnt  = goff + 1024;
    float* wtn  = (float*)(cnt + M);
    float* wts  = wtn + 2048;
    uintptr_t pc = (uintptr_t)(wts + 2048);
    pc = (pc + 15) & ~(uintptr_t)15;
    unsigned int* codes = (unsigned int*)pc;
    __half2* xws = (__half2*)(codes + (size_t)nb * CAP2);

    init_kernel<<<1, 512, 0, stream>>>(W_n, W_s, goff, wtn, wts, nb);
    place_kernel<<<dim3(SLICES, 2), 512, 0, stream>>>(ei_n, ei_s, goff, codes,
                                                      En, Es, nb);
    dcxw_kernel<<<(nb + 1) / 2, 256, 0, stream>>>(codes, goff, x, wtn, wts,
                                                  cnt, xws, N, M, nb);
    gather_kernel<<<nb, 1024, 0, stream>>>(codes, goff, xws, cnt,
                                           b_n, b_s, W_lin, b_lin, out, N);
}